// Round 14
// baseline (104.061 us; speedup 1.0000x reference)
//
#include <hip/hip_runtime.h>
#include <hip/hip_bf16.h>

typedef __attribute__((ext_vector_type(8)))  short bf16x8;
typedef __attribute__((ext_vector_type(16))) float f32x16;
typedef __attribute__((ext_vector_type(4)))  float f32x4;
typedef __attribute__((ext_vector_type(2)))  unsigned int u32x2;
typedef __attribute__((ext_vector_type(4)))  unsigned int u32x4;

#define NN 4096
#define CH 256
#define CQ 32

union UB { u32x4 u; bf16x8 h; };

static __device__ __forceinline__ ushort f2bf(float f) {
    __hip_bfloat16 h = __float2bfloat16(f);
    return *reinterpret_cast<ushort*>(&h);
}
static __device__ __forceinline__ uint pack2bf(float a, float b) {
    return (uint)f2bf(a) | ((uint)f2bf(b) << 16);
}
// single-instruction bf16 pair pack (T12)
static __device__ __forceinline__ uint cvt_pk_bf16(float a, float b) {
    uint r;
    asm("v_cvt_pk_bf16_f32 %0, %1, %2" : "=v"(r) : "v"(a), "v"(b));
    return r;
}
static __device__ __forceinline__ int swz(int n) {   // 3-bit 16B-slot swizzle
    return ((n & 7) ^ ((n >> 3) & 7)) << 4;
}
// lgkm-only barrier: publishes LDS writes, leaves global loads in flight (T4)
static __device__ __forceinline__ void sync_lds() {
    asm volatile("s_waitcnt lgkmcnt(0)" ::: "memory");
    __builtin_amdgcn_s_barrier();
    __builtin_amdgcn_sched_barrier(0);
}

// ---------------------------------------------------------------------------
// Fragment-tiled workspace layouts (bf16, 32x32 tiles of 1024 ushorts,
// in-tile offset = frag*512u + lane*8u). Frag loads: 64 lanes x 16B = 16 full
// 64B lines, wave-uniform SGPR base + constant offset.
// ---------------------------------------------------------------------------

// Fused Q/K/V projection, bf16 MFMA. grid (32 nblk, 5 chb, 4 b), block 256.
__global__ __launch_bounds__(256) void proj_mfma(
    const float* __restrict__ x,
    const float* __restrict__ Wq, const float* __restrict__ bq,
    const float* __restrict__ Wk, const float* __restrict__ bk,
    const float* __restrict__ Wv, const float* __restrict__ bv,
    ushort* __restrict__ qT, ushort* __restrict__ kT, ushort* __restrict__ v)
{
    const int nblk = blockIdx.x;
    const int chb  = blockIdx.y;
    const int b    = blockIdx.z;
    const int t    = threadIdx.x;
    const int w    = t >> 6;
    const int wc   = w >> 1, wn = w & 1;
    const int lane = t & 63;
    const int l31  = lane & 31;
    const int h5   = lane >> 5;

    __shared__ ushort Wl[64 * 256];     // 32 KB  [ch][c] bf16, 512B rows, swizzled
    __shared__ ushort Xl[128 * 64];     // 16 KB  [n][c]  bf16, 128B rows, swizzled

    // ---- stage W (64 out-ch x 256 c) fp32 -> bf16, once ----
    {
        const int ch  = t >> 2;
        const int c0  = (t & 3) * 64;
        const int chg = chb * 64 + ch;
        const float* wr; float sc = 1.0f;
        if (chg < 256)      wr = Wv + (size_t)chg * CH;
        else if (chg < 288) { wr = Wq + (size_t)(chg - 256) * CH; sc = 1.44269504f; }
        else                wr = Wk + (size_t)(chg - 288) * CH;
        const int sw = swz(ch);
#pragma unroll
        for (int j = 0; j < 16; ++j) {
            const int c = c0 + 4 * j;
            float4 f = *reinterpret_cast<const float4*>(wr + c);
            u32x2 p; p.x = pack2bf(f.x * sc, f.y * sc); p.y = pack2bf(f.z * sc, f.w * sc);
            *reinterpret_cast<u32x2*>((char*)Wl + ((ch * 512 + c * 2) ^ sw)) = p;
        }
    }

    const f32x16 z16 = {0,0,0,0, 0,0,0,0, 0,0,0,0, 0,0,0,0};
    f32x16 acc0 = z16, acc1 = z16;
    const float* xb = x + (size_t)b * CH * NN + nblk * 128;

    for (int cs = 0; cs < 4; ++cs) {
        if (cs) __syncthreads();
#pragma unroll
        for (int half = 0; half < 2; ++half) {
            const int cl0 = half * 32 + 4 * (t >> 5);
            const int nl0 = 4 * (t & 31);
            const float4 r0 = *reinterpret_cast<const float4*>(xb + (size_t)(cs*64 + cl0 + 0) * NN + nl0);
            const float4 r1 = *reinterpret_cast<const float4*>(xb + (size_t)(cs*64 + cl0 + 1) * NN + nl0);
            const float4 r2 = *reinterpret_cast<const float4*>(xb + (size_t)(cs*64 + cl0 + 2) * NN + nl0);
            const float4 r3 = *reinterpret_cast<const float4*>(xb + (size_t)(cs*64 + cl0 + 3) * NN + nl0);
#pragma unroll
            for (int e = 0; e < 4; ++e) {
                const int nl = nl0 + e;
                u32x2 p;
                p.x = pack2bf(((const float*)&r0)[e], ((const float*)&r1)[e]);
                p.y = pack2bf(((const float*)&r2)[e], ((const float*)&r3)[e]);
                *reinterpret_cast<u32x2*>((char*)Xl + ((nl * 128 + cl0 * 2) ^ swz(nl))) = p;
            }
        }
        __syncthreads();
#pragma unroll
        for (int kl = 0; kl < 4; ++kl) {
            const int ks  = cs * 4 + kl;
            const int chl = 32 * wc + l31;
            const bf16x8 af = *reinterpret_cast<const bf16x8*>(
                (char*)Wl + ((chl * 512 + ks * 32 + h5 * 16) ^ swz(chl)));
            {
                const int nl = 64 * wn + l31;
                const bf16x8 bfv = *reinterpret_cast<const bf16x8*>(
                    (char*)Xl + ((nl * 128 + kl * 32 + h5 * 16) ^ swz(nl)));
                acc0 = __builtin_amdgcn_mfma_f32_32x32x16_bf16(af, bfv, acc0, 0, 0, 0);
            }
            {
                const int nl = 64 * wn + 32 + l31;
                const bf16x8 bfv = *reinterpret_cast<const bf16x8*>(
                    (char*)Xl + ((nl * 128 + kl * 32 + h5 * 16) ^ swz(nl)));
                acc1 = __builtin_amdgcn_mfma_f32_32x32x16_bf16(af, bfv, acc1, 0, 0, 0);
            }
        }
    }

    // ---- epilogue: bias + store in fragment-tiled layouts ----
    const int chbase = chb * 64 + 32 * wc;
    if (chb < 4) {
        ushort* vtb = v + (size_t)b * 8 * 128 * 1024;
#pragma unroll
        for (int nt = 0; nt < 2; ++nt) {
            const f32x16 a = nt ? acc1 : acc0;
            const int key = nblk * 128 + 64 * wn + 32 * nt + l31;
            const size_t kb2 = (size_t)(key >> 5) * 1024
                             + ((key >> 4) & 1) * 512 + ((key >> 3) & 1) * 256 + (key & 7);
#pragma unroll
            for (int r = 0; r < 16; ++r) {
                const int ch = chbase + (r & 3) + 8 * (r >> 2) + 4 * h5;
                vtb[(size_t)(ch >> 5) * 128 * 1024 + kb2 + (ch & 31) * 8] = f2bf(a[r] + bv[ch]);
            }
        }
    } else {
        ushort* dst = (wc == 0 ? qT : kT) + (size_t)b * 128 * 1024;
        const float* bs = (wc == 0 ? bq : bk);
        const float bsc = (wc == 0) ? 1.44269504f : 1.0f;
#pragma unroll
        for (int nt = 0; nt < 2; ++nt) {
            const f32x16 a = nt ? acc1 : acc0;
            const int n = nblk * 128 + 64 * wn + 32 * nt + l31;
            uint* tb = (uint*)(dst + (size_t)(n >> 5) * 1024);
#pragma unroll
            for (int r = 0; r < 16; r += 2) {
                const int row = (r & 3) + 8 * (r >> 2) + 4 * h5;   // even
                tb[((row >> 4) & 1) * 256 + ((row >> 3) & 1) * 128 + (n & 31) * 4 + ((row & 7) >> 1)] =
                    pack2bf(a[r] + bs[row] * bsc, a[r + 1] + bs[row + 1] * bsc);
            }
        }
    }
}

// ---------------------------------------------------------------------------
// Flash attention v13: NO-DUPLICATION decomposition. 8 waves = (ct 0..3
// channel-quarters) x (qt 0..1 query-halves); each wave owns a DISJOINT
// 64ch x 32q output tile -> acc = 2 x f32x16 = 32 AGPR (vs v7's 128), no
// output reduction. Per 256-key superiter (16 total): wave S-computes its 2
// private key-chunks for its qt (QK^T computed exactly once block-wide),
// exp+cvt_pk+permlane in-register, publishes packed P to dbuf LDS pex;
// ONE lgkm barrier; PV over all 8 chunks reading P from LDS and V coalesced
// from L2. Register budget ~140 -> real ILP headroom at 2 waves/SIMD.
// grid 256 (batch locked to XCD pair), block 512.
// ---------------------------------------------------------------------------
__global__ __launch_bounds__(512) void attn_v13(
    const ushort* __restrict__ qT, const ushort* __restrict__ kT,
    const ushort* __restrict__ v, float* __restrict__ out)
{
    const int bid  = blockIdx.x;
    const int xcd  = bid & 7;
    const int b    = xcd >> 1;                       // batch locked to XCD pair
    const int qblk = (bid >> 3) + 32 * (xcd & 1);    // 0..63 per batch
    const int i0   = qblk * 64;

    const int t    = threadIdx.x;
    const int w    = t >> 6;
    const int qt   = w >> 2;          // query half 0..1 (32 q each)
    const int ctw  = w & 3;           // channel quarter 0..3 (64 ch each)
    const int lane = t & 63;
    const int l31  = lane & 31;
    const int h5   = lane >> 5;
    const int lo8  = lane * 8;        // frag lane offset (ushort units)

    __shared__ u32x4 pex[2][2][8][2][64];   // 64 KB [db][qt][chunk][frag][lane]
    __shared__ float red[2][4][32];         // 1 KB denominators [qt][ct][q]

    // wave-uniform bases (lane offset added only at deref)
    const ushort* qTb = qT + (size_t)b * 128 * 1024;
    const ushort* kTb = kT + (size_t)b * 128 * 1024;
    const ushort* vfb = v + (((size_t)b * 8 + 2 * ctw) * 128) * 1024;  // 2 ch-tiles

    // Q B-frags for own query half (col = query l31), contraction 32 in 2 ksteps
    const bf16x8 qf0 = *reinterpret_cast<const bf16x8*>(
        qTb + (size_t)(qblk * 2 + qt) * 1024 + lo8);
    const bf16x8 qf1 = *reinterpret_cast<const bf16x8*>(
        qTb + (size_t)(qblk * 2 + qt) * 1024 + 512 + lo8);

    const f32x16 z16 = {0,0,0,0, 0,0,0,0, 0,0,0,0, 0,0,0,0};
    f32x16 acc0 = z16, acc1 = z16;    // ch-tile 0 / 1 of own 64 channels
    float ts = 0.f;

    auto expack = [&](const f32x16& s, u32x4& o0, u32x4& o1) {
        float p[16];
#pragma unroll
        for (int r = 0; r < 16; ++r) p[r] = __builtin_exp2f(s[r]);
        ts += (((p[0]+p[1])+(p[2]+p[3])) + ((p[4]+p[5])+(p[6]+p[7])))
            + (((p[8]+p[9])+(p[10]+p[11])) + ((p[12]+p[13])+(p[14]+p[15])));
        const uint pk0 = cvt_pk_bf16(p[0],  p[1]);
        const uint pk1 = cvt_pk_bf16(p[2],  p[3]);
        const uint pk2 = cvt_pk_bf16(p[4],  p[5]);
        const uint pk3 = cvt_pk_bf16(p[6],  p[7]);
        const uint pk4 = cvt_pk_bf16(p[8],  p[9]);
        const uint pk5 = cvt_pk_bf16(p[10], p[11]);
        const uint pk6 = cvt_pk_bf16(p[12], p[13]);
        const uint pk7 = cvt_pk_bf16(p[14], p[15]);
        const u32x2 s02 = __builtin_amdgcn_permlane32_swap(pk0, pk2, false, false);
        const u32x2 s13 = __builtin_amdgcn_permlane32_swap(pk1, pk3, false, false);
        const u32x2 s46 = __builtin_amdgcn_permlane32_swap(pk4, pk6, false, false);
        const u32x2 s57 = __builtin_amdgcn_permlane32_swap(pk5, pk7, false, false);
        o0 = u32x4{ s02.x, s13.x, s02.y, s13.y };   // keys 8h5..+7   (ks0)
        o1 = u32x4{ s46.x, s57.x, s46.y, s57.y };   // keys 16+8h5..+7 (ks1)
    };

#pragma unroll 1
    for (int it = 0; it < 16; ++it) {
        const int db = it & 1;
        const int tile0 = it * 8;

        // ---- Phase A: S on this wave's 2 private chunks (ctw, ctw+4) ----
        {
            const ushort* ka = kTb + (size_t)(tile0 + ctw) * 1024;
            const ushort* kb = kTb + (size_t)(tile0 + ctw + 4) * 1024;
            const bf16x8 ka0 = *reinterpret_cast<const bf16x8*>(ka + lo8);
            const bf16x8 ka1 = *reinterpret_cast<const bf16x8*>(ka + 512 + lo8);
            const bf16x8 kb0 = *reinterpret_cast<const bf16x8*>(kb + lo8);
            const bf16x8 kb1 = *reinterpret_cast<const bf16x8*>(kb + 512 + lo8);
            f32x16 sa = __builtin_amdgcn_mfma_f32_32x32x16_bf16(ka0, qf0, z16, 0, 0, 0);
            sa = __builtin_amdgcn_mfma_f32_32x32x16_bf16(ka1, qf1, sa, 0, 0, 0);
            f32x16 sb = __builtin_amdgcn_mfma_f32_32x32x16_bf16(kb0, qf0, z16, 0, 0, 0);
            sb = __builtin_amdgcn_mfma_f32_32x32x16_bf16(kb1, qf1, sb, 0, 0, 0);
            u32x4 a0, a1, b0, b1;
            expack(sa, a0, a1);
            expack(sb, b0, b1);
            pex[db][qt][ctw][0][lane] = a0;
            pex[db][qt][ctw][1][lane] = a1;
            pex[db][qt][ctw + 4][0][lane] = b0;
            pex[db][qt][ctw + 4][1][lane] = b1;
        }

        sync_lds();   // publish pex[db]; V loads may stay in flight

        // ---- Phase B: PV over all 8 chunks (P from LDS, V from L2) ----
#pragma unroll
        for (int cc = 0; cc < 8; ++cc) {
            const ushort* vb = vfb + (size_t)(tile0 + cc) * 1024;
            const bf16x8 v00 = *reinterpret_cast<const bf16x8*>(vb + lo8);
            const bf16x8 v01 = *reinterpret_cast<const bf16x8*>(vb + 512 + lo8);
            const bf16x8 v10 = *reinterpret_cast<const bf16x8*>(vb + 131072 + lo8);
            const bf16x8 v11 = *reinterpret_cast<const bf16x8*>(vb + 131072 + 512 + lo8);
            UB pf0, pf1;
            pf0.u = pex[db][qt][cc][0][lane];
            pf1.u = pex[db][qt][cc][1][lane];
            acc0 = __builtin_amdgcn_mfma_f32_32x32x16_bf16(v00, pf0.h, acc0, 0, 0, 0);
            acc0 = __builtin_amdgcn_mfma_f32_32x32x16_bf16(v01, pf1.h, acc0, 0, 0, 0);
            acc1 = __builtin_amdgcn_mfma_f32_32x32x16_bf16(v10, pf0.h, acc1, 0, 0, 0);
            acc1 = __builtin_amdgcn_mfma_f32_32x32x16_bf16(v11, pf1.h, acc1, 0, 0, 0);
        }
    }

    // ---- denominators: per-wave partial covers its private key chunks ----
    ts += __shfl_xor(ts, 32);
    if (lane < 32) red[qt][ctw][l31] = ts;
    __syncthreads();
    const float inv = 1.0f / (red[qt][0][l31] + red[qt][1][l31]
                            + red[qt][2][l31] + red[qt][3][l31]);

    // ---- direct store: wave owns disjoint 64ch x 32q ----
    float* ob = out + (size_t)b * CH * NN + i0 + 32 * qt;
#pragma unroll
    for (int cht = 0; cht < 2; ++cht) {
        const f32x16 a = cht ? acc1 : acc0;
#pragma unroll
        for (int r = 0; r < 16; ++r) {
            const int chl = 64 * ctw + 32 * cht + (r & 3) + 8 * (r >> 2) + 4 * h5;
            ob[(size_t)chl * NN + l31] = a[r] * inv;
        }
    }
}

extern "C" void kernel_launch(void* const* d_in, const int* in_sizes, int n_in,
                              void* d_out, int out_size, void* d_ws, size_t ws_size,
                              hipStream_t stream) {
    const float* x  = (const float*)d_in[0];
    const float* Wq = (const float*)d_in[1];
    const float* bq = (const float*)d_in[2];
    const float* Wk = (const float*)d_in[3];
    const float* bk = (const float*)d_in[4];
    const float* Wv = (const float*)d_in[5];
    const float* bv = (const float*)d_in[6];
    float* out = (float*)d_out;

    ushort* ws = (ushort*)d_ws;
    ushort* qTf = ws;                                   // 4*128 tiles * 2KB = 1 MB
    ushort* kTf = qTf + (size_t)4 * 128 * 1024;         // 1 MB
    ushort* vf  = kTf + (size_t)4 * 128 * 1024;         // 4*8*128 tiles * 2KB = 8 MB

    proj_mfma<<<dim3(32, 5, 4), 256, 0, stream>>>(x, Wq, bq, Wk, bk, Wv, bv, qTf, kTf, vf);
    attn_v13<<<dim3(256), 512, 0, stream>>>(qTf, kTf, vf, out);
}

// Round 15
// 85.755 us; speedup vs baseline: 1.2135x; 1.2135x over previous
//
#include <hip/hip_runtime.h>
#include <hip/hip_bf16.h>

typedef __attribute__((ext_vector_type(8)))  short bf16x8;
typedef __attribute__((ext_vector_type(16))) float f32x16;
typedef __attribute__((ext_vector_type(4)))  float f32x4;
typedef __attribute__((ext_vector_type(2)))  unsigned int u32x2;
typedef __attribute__((ext_vector_type(4)))  unsigned int u32x4;

#define NN 4096
#define CH 256
#define CQ 32

union UB { u32x4 u; bf16x8 h; };

static __device__ __forceinline__ ushort f2bf(float f) {
    __hip_bfloat16 h = __float2bfloat16(f);
    return *reinterpret_cast<ushort*>(&h);
}
static __device__ __forceinline__ uint pack2bf(float a, float b) {
    return (uint)f2bf(a) | ((uint)f2bf(b) << 16);
}
// single-instruction bf16 pair pack (T12)
static __device__ __forceinline__ uint cvt_pk_bf16(float a, float b) {
    uint r;
    asm("v_cvt_pk_bf16_f32 %0, %1, %2" : "=v"(r) : "v"(a), "v"(b));
    return r;
}
static __device__ __forceinline__ int swz(int n) {   // 3-bit 16B-slot swizzle
    return ((n & 7) ^ ((n >> 3) & 7)) << 4;
}
// lgkm-only barrier: publishes LDS writes, leaves global loads in flight (T4)
static __device__ __forceinline__ void sync_lds() {
    asm volatile("s_waitcnt lgkmcnt(0)" ::: "memory");
    __builtin_amdgcn_s_barrier();
    __builtin_amdgcn_sched_barrier(0);
}

// ---------------------------------------------------------------------------
// Fragment-tiled workspace layouts (bf16, 32x32 tiles of 1024 ushorts,
// in-tile offset = frag*512u + lane*8u). Frag loads: 64 lanes x 16B = 16 full
// 64B lines, wave-uniform SGPR base + constant offset.
// ---------------------------------------------------------------------------

// Fused Q/K/V projection, bf16 MFMA. grid (32 nblk, 5 chb, 4 b), block 256.
__global__ __launch_bounds__(256) void proj_mfma(
    const float* __restrict__ x,
    const float* __restrict__ Wq, const float* __restrict__ bq,
    const float* __restrict__ Wk, const float* __restrict__ bk,
    const float* __restrict__ Wv, const float* __restrict__ bv,
    ushort* __restrict__ qT, ushort* __restrict__ kT, ushort* __restrict__ v)
{
    const int nblk = blockIdx.x;
    const int chb  = blockIdx.y;
    const int b    = blockIdx.z;
    const int t    = threadIdx.x;
    const int w    = t >> 6;
    const int wc   = w >> 1, wn = w & 1;
    const int lane = t & 63;
    const int l31  = lane & 31;
    const int h5   = lane >> 5;

    __shared__ ushort Wl[64 * 256];     // 32 KB  [ch][c] bf16, 512B rows, swizzled
    __shared__ ushort Xl[128 * 64];     // 16 KB  [n][c]  bf16, 128B rows, swizzled

    // ---- stage W (64 out-ch x 256 c) fp32 -> bf16, once ----
    {
        const int ch  = t >> 2;
        const int c0  = (t & 3) * 64;
        const int chg = chb * 64 + ch;
        const float* wr; float sc = 1.0f;
        if (chg < 256)      wr = Wv + (size_t)chg * CH;
        else if (chg < 288) { wr = Wq + (size_t)(chg - 256) * CH; sc = 1.44269504f; }
        else                wr = Wk + (size_t)(chg - 288) * CH;
        const int sw = swz(ch);
#pragma unroll
        for (int j = 0; j < 16; ++j) {
            const int c = c0 + 4 * j;
            float4 f = *reinterpret_cast<const float4*>(wr + c);
            u32x2 p; p.x = pack2bf(f.x * sc, f.y * sc); p.y = pack2bf(f.z * sc, f.w * sc);
            *reinterpret_cast<u32x2*>((char*)Wl + ((ch * 512 + c * 2) ^ sw)) = p;
        }
    }

    const f32x16 z16 = {0,0,0,0, 0,0,0,0, 0,0,0,0, 0,0,0,0};
    f32x16 acc0 = z16, acc1 = z16;
    const float* xb = x + (size_t)b * CH * NN + nblk * 128;

    for (int cs = 0; cs < 4; ++cs) {
        if (cs) __syncthreads();
#pragma unroll
        for (int half = 0; half < 2; ++half) {
            const int cl0 = half * 32 + 4 * (t >> 5);
            const int nl0 = 4 * (t & 31);
            const float4 r0 = *reinterpret_cast<const float4*>(xb + (size_t)(cs*64 + cl0 + 0) * NN + nl0);
            const float4 r1 = *reinterpret_cast<const float4*>(xb + (size_t)(cs*64 + cl0 + 1) * NN + nl0);
            const float4 r2 = *reinterpret_cast<const float4*>(xb + (size_t)(cs*64 + cl0 + 2) * NN + nl0);
            const float4 r3 = *reinterpret_cast<const float4*>(xb + (size_t)(cs*64 + cl0 + 3) * NN + nl0);
#pragma unroll
            for (int e = 0; e < 4; ++e) {
                const int nl = nl0 + e;
                u32x2 p;
                p.x = pack2bf(((const float*)&r0)[e], ((const float*)&r1)[e]);
                p.y = pack2bf(((const float*)&r2)[e], ((const float*)&r3)[e]);
                *reinterpret_cast<u32x2*>((char*)Xl + ((nl * 128 + cl0 * 2) ^ swz(nl))) = p;
            }
        }
        __syncthreads();
#pragma unroll
        for (int kl = 0; kl < 4; ++kl) {
            const int ks  = cs * 4 + kl;
            const int chl = 32 * wc + l31;
            const bf16x8 af = *reinterpret_cast<const bf16x8*>(
                (char*)Wl + ((chl * 512 + ks * 32 + h5 * 16) ^ swz(chl)));
            {
                const int nl = 64 * wn + l31;
                const bf16x8 bfv = *reinterpret_cast<const bf16x8*>(
                    (char*)Xl + ((nl * 128 + kl * 32 + h5 * 16) ^ swz(nl)));
                acc0 = __builtin_amdgcn_mfma_f32_32x32x16_bf16(af, bfv, acc0, 0, 0, 0);
            }
            {
                const int nl = 64 * wn + 32 + l31;
                const bf16x8 bfv = *reinterpret_cast<const bf16x8*>(
                    (char*)Xl + ((nl * 128 + kl * 32 + h5 * 16) ^ swz(nl)));
                acc1 = __builtin_amdgcn_mfma_f32_32x32x16_bf16(af, bfv, acc1, 0, 0, 0);
            }
        }
    }

    // ---- epilogue: bias + store in fragment-tiled layouts ----
    const int chbase = chb * 64 + 32 * wc;
    if (chb < 4) {
        ushort* vtb = v + (size_t)b * 8 * 128 * 1024;
#pragma unroll
        for (int nt = 0; nt < 2; ++nt) {
            const f32x16 a = nt ? acc1 : acc0;
            const int key = nblk * 128 + 64 * wn + 32 * nt + l31;
            const size_t kb2 = (size_t)(key >> 5) * 1024
                             + ((key >> 4) & 1) * 512 + ((key >> 3) & 1) * 256 + (key & 7);
#pragma unroll
            for (int r = 0; r < 16; ++r) {
                const int ch = chbase + (r & 3) + 8 * (r >> 2) + 4 * h5;
                vtb[(size_t)(ch >> 5) * 128 * 1024 + kb2 + (ch & 31) * 8] = f2bf(a[r] + bv[ch]);
            }
        }
    } else {
        ushort* dst = (wc == 0 ? qT : kT) + (size_t)b * 128 * 1024;
        const float* bs = (wc == 0 ? bq : bk);
        const float bsc = (wc == 0) ? 1.44269504f : 1.0f;
#pragma unroll
        for (int nt = 0; nt < 2; ++nt) {
            const f32x16 a = nt ? acc1 : acc0;
            const int n = nblk * 128 + 64 * wn + 32 * nt + l31;
            uint* tb = (uint*)(dst + (size_t)(n >> 5) * 1024);
#pragma unroll
            for (int r = 0; r < 16; r += 2) {
                const int row = (r & 3) + 8 * (r >> 2) + 4 * h5;   // even
                tb[((row >> 4) & 1) * 256 + ((row >> 3) & 1) * 128 + (n & 31) * 4 + ((row & 7) >> 1)] =
                    pack2bf(a[r] + bs[row] * bsc, a[r + 1] + bs[row + 1] * bsc);
            }
        }
    }
}

// ---------------------------------------------------------------------------
// Flash attention v14 = v13's no-duplication decomposition with its two
// failure causes removed:
//   * superiter = 512 keys -> pex dbuf 128 KB, only 8 block barriers total,
//     ~5k cyc of slack between barriers (waves drift within a superiter);
//     race-free: PV(it) precedes barrier(it+1) in program order, so a wave
//     writing pex[db] at it+2 implies all waves finished reading it at it.
//   * waves_per_eu(2,2) -> 256-reg budget at 2 waves/SIMD (v13's compiler
//     chose 60 VGPR targeting 4 waves -> serial loads).
// 8 waves = (qt 0..1 query-half) x (ctw 0..3 channel-quarter); each wave owns
// a DISJOINT 64ch x 32q tile -> acc 32 AGPR, no output reduction, QK^T and
// expack computed exactly once block-wide. s_setprio(1) around PV MFMAs (T5).
// grid 256 (batch locked to XCD pair), block 512.
// ---------------------------------------------------------------------------
__global__ __attribute__((amdgpu_flat_work_group_size(512, 512), amdgpu_waves_per_eu(2, 2)))
void attn_v14(
    const ushort* __restrict__ qT, const ushort* __restrict__ kT,
    const ushort* __restrict__ v, float* __restrict__ out)
{
    const int bid  = blockIdx.x;
    const int xcd  = bid & 7;
    const int b    = xcd >> 1;                       // batch locked to XCD pair
    const int qblk = (bid >> 3) + 32 * (xcd & 1);    // 0..63 per batch
    const int i0   = qblk * 64;

    const int t    = threadIdx.x;
    const int w    = t >> 6;
    const int qt   = w >> 2;          // query half 0..1 (32 q each)
    const int ctw  = w & 3;           // channel quarter 0..3 (64 ch each)
    const int lane = t & 63;
    const int l31  = lane & 31;
    const int h5   = lane >> 5;
    const int lo8  = lane * 8;        // frag lane offset (ushort units)

    __shared__ u32x4 pex[2][2][16][2][64];   // 128 KB [db][qt][chunk][frag][lane]
    __shared__ float red[2][4][32];          // 1 KB denominators [qt][ctw][q]

    // wave-uniform bases (lane offset added only at deref)
    const ushort* qTb = qT + (size_t)b * 128 * 1024;
    const ushort* kTb = kT + (size_t)b * 128 * 1024;
    const ushort* vfb = v + (((size_t)b * 8 + 2 * ctw) * 128) * 1024;  // 2 ch-tiles

    // Q B-frags for own query half (col = query l31), contraction 32 in 2 ksteps
    const bf16x8 qf0 = *reinterpret_cast<const bf16x8*>(
        qTb + (size_t)(qblk * 2 + qt) * 1024 + lo8);
    const bf16x8 qf1 = *reinterpret_cast<const bf16x8*>(
        qTb + (size_t)(qblk * 2 + qt) * 1024 + 512 + lo8);

    const f32x16 z16 = {0,0,0,0, 0,0,0,0, 0,0,0,0, 0,0,0,0};
    f32x16 acc0 = z16, acc1 = z16;    // ch-tile 0 / 1 of own 64 channels
    float ts = 0.f;

    auto expack = [&](const f32x16& s, u32x4& o0, u32x4& o1) {
        float p[16];
#pragma unroll
        for (int r = 0; r < 16; ++r) p[r] = __builtin_exp2f(s[r]);
        ts += (((p[0]+p[1])+(p[2]+p[3])) + ((p[4]+p[5])+(p[6]+p[7])))
            + (((p[8]+p[9])+(p[10]+p[11])) + ((p[12]+p[13])+(p[14]+p[15])));
        const uint pk0 = cvt_pk_bf16(p[0],  p[1]);
        const uint pk1 = cvt_pk_bf16(p[2],  p[3]);
        const uint pk2 = cvt_pk_bf16(p[4],  p[5]);
        const uint pk3 = cvt_pk_bf16(p[6],  p[7]);
        const uint pk4 = cvt_pk_bf16(p[8],  p[9]);
        const uint pk5 = cvt_pk_bf16(p[10], p[11]);
        const uint pk6 = cvt_pk_bf16(p[12], p[13]);
        const uint pk7 = cvt_pk_bf16(p[14], p[15]);
        const u32x2 s02 = __builtin_amdgcn_permlane32_swap(pk0, pk2, false, false);
        const u32x2 s13 = __builtin_amdgcn_permlane32_swap(pk1, pk3, false, false);
        const u32x2 s46 = __builtin_amdgcn_permlane32_swap(pk4, pk6, false, false);
        const u32x2 s57 = __builtin_amdgcn_permlane32_swap(pk5, pk7, false, false);
        o0 = u32x4{ s02.x, s13.x, s02.y, s13.y };   // keys 8h5..+7   (ks0)
        o1 = u32x4{ s46.x, s57.x, s46.y, s57.y };   // keys 16+8h5..+7 (ks1)
    };

#pragma unroll 1
    for (int si = 0; si < 8; ++si) {
        const int db = si & 1;
        const int tile0 = si * 16;

        // ---- Phase A: S + expack for my 4 private chunks (ctw + 4u) ----
        // group all 8 K-frag loads first (32 VGPR), then MFMAs, then expacks
        bf16x8 kf[4][2];
#pragma unroll
        for (int u = 0; u < 4; ++u) {
            const ushort* kr = kTb + (size_t)(tile0 + ctw + 4 * u) * 1024;
            kf[u][0] = *reinterpret_cast<const bf16x8*>(kr + lo8);
            kf[u][1] = *reinterpret_cast<const bf16x8*>(kr + 512 + lo8);
        }
        __builtin_amdgcn_sched_barrier(0);
#pragma unroll
        for (int u = 0; u < 4; ++u) {
            f32x16 s = __builtin_amdgcn_mfma_f32_32x32x16_bf16(kf[u][0], qf0, z16, 0, 0, 0);
            s = __builtin_amdgcn_mfma_f32_32x32x16_bf16(kf[u][1], qf1, s, 0, 0, 0);
            u32x4 a0, a1;
            expack(s, a0, a1);
            pex[db][qt][ctw + 4 * u][0][lane] = a0;
            pex[db][qt][ctw + 4 * u][1][lane] = a1;
        }

        sync_lds();   // ONE barrier per 512 keys; V/K loads stay in flight

        // ---- Phase B: PV over all 16 chunks x own 2 ch-tiles ----
#pragma unroll 2
        for (int cc = 0; cc < 16; ++cc) {
            const ushort* vb = vfb + (size_t)(tile0 + cc) * 1024;
            const bf16x8 v00 = *reinterpret_cast<const bf16x8*>(vb + lo8);
            const bf16x8 v01 = *reinterpret_cast<const bf16x8*>(vb + 512 + lo8);
            const bf16x8 v10 = *reinterpret_cast<const bf16x8*>(vb + 131072 + lo8);
            const bf16x8 v11 = *reinterpret_cast<const bf16x8*>(vb + 131072 + 512 + lo8);
            UB pf0, pf1;
            pf0.u = pex[db][qt][cc][0][lane];
            pf1.u = pex[db][qt][cc][1][lane];
            __builtin_amdgcn_s_setprio(1);
            acc0 = __builtin_amdgcn_mfma_f32_32x32x16_bf16(v00, pf0.h, acc0, 0, 0, 0);
            acc0 = __builtin_amdgcn_mfma_f32_32x32x16_bf16(v01, pf1.h, acc0, 0, 0, 0);
            acc1 = __builtin_amdgcn_mfma_f32_32x32x16_bf16(v10, pf0.h, acc1, 0, 0, 0);
            acc1 = __builtin_amdgcn_mfma_f32_32x32x16_bf16(v11, pf1.h, acc1, 0, 0, 0);
            __builtin_amdgcn_s_setprio(0);
        }
    }

    // ---- denominators: per-wave partial covers its private key chunks ----
    ts += __shfl_xor(ts, 32);
    if (lane < 32) red[qt][ctw][l31] = ts;
    __syncthreads();
    const float inv = 1.0f / (red[qt][0][l31] + red[qt][1][l31]
                            + red[qt][2][l31] + red[qt][3][l31]);

    // ---- direct store: wave owns disjoint 64ch x 32q ----
    float* ob = out + (size_t)b * CH * NN + i0 + 32 * qt;
#pragma unroll
    for (int cht = 0; cht < 2; ++cht) {
        const f32x16 a = cht ? acc1 : acc0;
#pragma unroll
        for (int r = 0; r < 16; ++r) {
            const int chl = 64 * ctw + 32 * cht + (r & 3) + 8 * (r >> 2) + 4 * h5;
            ob[(size_t)chl * NN + l31] = a[r] * inv;
        }
    }
}

extern "C" void kernel_launch(void* const* d_in, const int* in_sizes, int n_in,
                              void* d_out, int out_size, void* d_ws, size_t ws_size,
                              hipStream_t stream) {
    const float* x  = (const float*)d_in[0];
    const float* Wq = (const float*)d_in[1];
    const float* bq = (const float*)d_in[2];
    const float* Wk = (const float*)d_in[3];
    const float* bk = (const float*)d_in[4];
    const float* Wv = (const float*)d_in[5];
    const float* bv = (const float*)d_in[6];
    float* out = (float*)d_out;

    ushort* ws = (ushort*)d_ws;
    ushort* qTf = ws;                                   // 4*128 tiles * 2KB = 1 MB
    ushort* kTf = qTf + (size_t)4 * 128 * 1024;         // 1 MB
    ushort* vf  = kTf + (size_t)4 * 128 * 1024;         // 4*8*128 tiles * 2KB = 8 MB

    proj_mfma<<<dim3(32, 5, 4), 256, 0, stream>>>(x, Wq, bq, Wk, bk, Wv, bv, qTf, kTf, vf);
    attn_v14<<<dim3(256), 512, 0, stream>>>(qTf, kTf, vf, out);
}

// Round 16
// 83.244 us; speedup vs baseline: 1.2501x; 1.0302x over previous
//
#include <hip/hip_runtime.h>
#include <hip/hip_bf16.h>

typedef __attribute__((ext_vector_type(8)))  short bf16x8;
typedef __attribute__((ext_vector_type(16))) float f32x16;
typedef __attribute__((ext_vector_type(4)))  float f32x4;
typedef __attribute__((ext_vector_type(2)))  unsigned int u32x2;
typedef __attribute__((ext_vector_type(4)))  unsigned int u32x4;

#define NN 4096
#define CH 256
#define CQ 32

union UB { u32x4 u; bf16x8 h; };

static __device__ __forceinline__ ushort f2bf(float f) {
    __hip_bfloat16 h = __float2bfloat16(f);
    return *reinterpret_cast<ushort*>(&h);
}
static __device__ __forceinline__ uint pack2bf(float a, float b) {
    return (uint)f2bf(a) | ((uint)f2bf(b) << 16);
}
// single-instruction bf16 pair pack (T12)
static __device__ __forceinline__ uint cvt_pk_bf16(float a, float b) {
    uint r;
    asm("v_cvt_pk_bf16_f32 %0, %1, %2" : "=v"(r) : "v"(a), "v"(b));
    return r;
}
static __device__ __forceinline__ int swz(int n) {   // 3-bit 16B-slot swizzle
    return ((n & 7) ^ ((n >> 3) & 7)) << 4;
}
// lgkm-only barrier: publishes LDS writes, leaves global loads in flight (T4)
static __device__ __forceinline__ void sync_lds() {
    asm volatile("s_waitcnt lgkmcnt(0)" ::: "memory");
    __builtin_amdgcn_s_barrier();
    __builtin_amdgcn_sched_barrier(0);
}

// ---------------------------------------------------------------------------
// Fragment-tiled workspace layouts (bf16, 32x32 tiles of 1024 ushorts,
// in-tile offset = frag*512u + lane*8u). Frag loads: 64 lanes x 16B = 16 full
// 64B lines, wave-uniform SGPR base + constant offset.
// ---------------------------------------------------------------------------

// Fused Q/K/V projection, bf16 MFMA. grid (32 nblk, 5 chb, 4 b), block 256.
__global__ __launch_bounds__(256) void proj_mfma(
    const float* __restrict__ x,
    const float* __restrict__ Wq, const float* __restrict__ bq,
    const float* __restrict__ Wk, const float* __restrict__ bk,
    const float* __restrict__ Wv, const float* __restrict__ bv,
    ushort* __restrict__ qT, ushort* __restrict__ kT, ushort* __restrict__ v)
{
    const int nblk = blockIdx.x;
    const int chb  = blockIdx.y;
    const int b    = blockIdx.z;
    const int t    = threadIdx.x;
    const int w    = t >> 6;
    const int wc   = w >> 1, wn = w & 1;
    const int lane = t & 63;
    const int l31  = lane & 31;
    const int h5   = lane >> 5;

    __shared__ ushort Wl[64 * 256];     // 32 KB  [ch][c] bf16, 512B rows, swizzled
    __shared__ ushort Xl[128 * 64];     // 16 KB  [n][c]  bf16, 128B rows, swizzled

    // ---- stage W (64 out-ch x 256 c) fp32 -> bf16, once ----
    {
        const int ch  = t >> 2;
        const int c0  = (t & 3) * 64;
        const int chg = chb * 64 + ch;
        const float* wr; float sc = 1.0f;
        if (chg < 256)      wr = Wv + (size_t)chg * CH;
        else if (chg < 288) { wr = Wq + (size_t)(chg - 256) * CH; sc = 1.44269504f; }
        else                wr = Wk + (size_t)(chg - 288) * CH;
        const int sw = swz(ch);
#pragma unroll
        for (int j = 0; j < 16; ++j) {
            const int c = c0 + 4 * j;
            float4 f = *reinterpret_cast<const float4*>(wr + c);
            u32x2 p; p.x = pack2bf(f.x * sc, f.y * sc); p.y = pack2bf(f.z * sc, f.w * sc);
            *reinterpret_cast<u32x2*>((char*)Wl + ((ch * 512 + c * 2) ^ sw)) = p;
        }
    }

    const f32x16 z16 = {0,0,0,0, 0,0,0,0, 0,0,0,0, 0,0,0,0};
    f32x16 acc0 = z16, acc1 = z16;
    const float* xb = x + (size_t)b * CH * NN + nblk * 128;

    for (int cs = 0; cs < 4; ++cs) {
        if (cs) __syncthreads();
#pragma unroll
        for (int half = 0; half < 2; ++half) {
            const int cl0 = half * 32 + 4 * (t >> 5);
            const int nl0 = 4 * (t & 31);
            const float4 r0 = *reinterpret_cast<const float4*>(xb + (size_t)(cs*64 + cl0 + 0) * NN + nl0);
            const float4 r1 = *reinterpret_cast<const float4*>(xb + (size_t)(cs*64 + cl0 + 1) * NN + nl0);
            const float4 r2 = *reinterpret_cast<const float4*>(xb + (size_t)(cs*64 + cl0 + 2) * NN + nl0);
            const float4 r3 = *reinterpret_cast<const float4*>(xb + (size_t)(cs*64 + cl0 + 3) * NN + nl0);
#pragma unroll
            for (int e = 0; e < 4; ++e) {
                const int nl = nl0 + e;
                u32x2 p;
                p.x = pack2bf(((const float*)&r0)[e], ((const float*)&r1)[e]);
                p.y = pack2bf(((const float*)&r2)[e], ((const float*)&r3)[e]);
                *reinterpret_cast<u32x2*>((char*)Xl + ((nl * 128 + cl0 * 2) ^ swz(nl))) = p;
            }
        }
        __syncthreads();
#pragma unroll
        for (int kl = 0; kl < 4; ++kl) {
            const int ks  = cs * 4 + kl;
            const int chl = 32 * wc + l31;
            const bf16x8 af = *reinterpret_cast<const bf16x8*>(
                (char*)Wl + ((chl * 512 + ks * 32 + h5 * 16) ^ swz(chl)));
            {
                const int nl = 64 * wn + l31;
                const bf16x8 bfv = *reinterpret_cast<const bf16x8*>(
                    (char*)Xl + ((nl * 128 + kl * 32 + h5 * 16) ^ swz(nl)));
                acc0 = __builtin_amdgcn_mfma_f32_32x32x16_bf16(af, bfv, acc0, 0, 0, 0);
            }
            {
                const int nl = 64 * wn + 32 + l31;
                const bf16x8 bfv = *reinterpret_cast<const bf16x8*>(
                    (char*)Xl + ((nl * 128 + kl * 32 + h5 * 16) ^ swz(nl)));
                acc1 = __builtin_amdgcn_mfma_f32_32x32x16_bf16(af, bfv, acc1, 0, 0, 0);
            }
        }
    }

    // ---- epilogue: bias + store in fragment-tiled layouts ----
    const int chbase = chb * 64 + 32 * wc;
    if (chb < 4) {
        ushort* vtb = v + (size_t)b * 8 * 128 * 1024;
#pragma unroll
        for (int nt = 0; nt < 2; ++nt) {
            const f32x16 a = nt ? acc1 : acc0;
            const int key = nblk * 128 + 64 * wn + 32 * nt + l31;
            const size_t kb2 = (size_t)(key >> 5) * 1024
                             + ((key >> 4) & 1) * 512 + ((key >> 3) & 1) * 256 + (key & 7);
#pragma unroll
            for (int r = 0; r < 16; ++r) {
                const int ch = chbase + (r & 3) + 8 * (r >> 2) + 4 * h5;
                vtb[(size_t)(ch >> 5) * 128 * 1024 + kb2 + (ch & 31) * 8] = f2bf(a[r] + bv[ch]);
            }
        }
    } else {
        ushort* dst = (wc == 0 ? qT : kT) + (size_t)b * 128 * 1024;
        const float* bs = (wc == 0 ? bq : bk);
        const float bsc = (wc == 0) ? 1.44269504f : 1.0f;
#pragma unroll
        for (int nt = 0; nt < 2; ++nt) {
            const f32x16 a = nt ? acc1 : acc0;
            const int n = nblk * 128 + 64 * wn + 32 * nt + l31;
            uint* tb = (uint*)(dst + (size_t)(n >> 5) * 1024);
#pragma unroll
            for (int r = 0; r < 16; r += 2) {
                const int row = (r & 3) + 8 * (r >> 2) + 4 * h5;   // even
                tb[((row >> 4) & 1) * 256 + ((row >> 3) & 1) * 128 + (n & 31) * 4 + ((row & 7) >> 1)] =
                    pack2bf(a[r] + bs[row] * bsc, a[r + 1] + bs[row + 1] * bsc);
            }
        }
    }
}

// ---------------------------------------------------------------------------
// Flash attention v15 = v14's dedup + v7's read-once V traffic:
//   * 8 waves = 8 DISJOINT 32-channel groups, each owning ALL 64 queries
//     -> V read exactly once block-wide (32 loads/superiter/wave, half v14),
//        acc = 2 x f32x16 = 32 AGPR, direct store, no output reduction.
//   * S dedup'd: wave computes S only for its 2 private key-chunks per
//     512-key superiter (both query halves; 4 expacks/wave), shares packed
//     P via 128 KB double-buffered pex with ONE lgkm barrier per superiter
//     (8 total). Race-free: PV(si) precedes barrier(si+1) in program order.
//   * waves_per_eu(2,2): 256-reg budget at 2 waves/SIMD.
// grid 256 (batch locked to XCD pair), block 512.
// ---------------------------------------------------------------------------
__global__ __attribute__((amdgpu_flat_work_group_size(512, 512), amdgpu_waves_per_eu(2, 2)))
void attn_v15(
    const ushort* __restrict__ qT, const ushort* __restrict__ kT,
    const ushort* __restrict__ v, float* __restrict__ out)
{
    const int bid  = blockIdx.x;
    const int xcd  = bid & 7;
    const int b    = xcd >> 1;                       // batch locked to XCD pair
    const int qblk = (bid >> 3) + 32 * (xcd & 1);    // 0..63 per batch
    const int i0   = qblk * 64;

    const int t    = threadIdx.x;
    const int w    = t >> 6;          // 0..7 = disjoint 32-channel group
    const int lane = t & 63;
    const int l31  = lane & 31;
    const int h5   = lane >> 5;
    const int lo8  = lane * 8;        // frag lane offset (ushort units)

    __shared__ u32x4 pex[2][16][2][2][64];   // 128 KB [db][chunk][qt][frag][lane]
    __shared__ float red[2][8][32];          // 2 KB denominators [qt][w][q]

    // wave-uniform bases (lane offset added only at deref)
    const ushort* qTb = qT + (size_t)b * 128 * 1024;
    const ushort* kTb = kT + (size_t)b * 128 * 1024;
    const ushort* vTb = v + (((size_t)b * 8 + w) * 128) * 1024;   // own 32-ch tile row

    // Q B-frags, both query halves (col = query l31), contraction 32 in 2 ksteps
    bf16x8 qf[2][2];
#pragma unroll
    for (int qt = 0; qt < 2; ++qt)
#pragma unroll
        for (int ks = 0; ks < 2; ++ks)
            qf[qt][ks] = *reinterpret_cast<const bf16x8*>(
                qTb + (size_t)(qblk * 2 + qt) * 1024 + ks * 512 + lo8);

    const f32x16 z16 = {0,0,0,0, 0,0,0,0, 0,0,0,0, 0,0,0,0};
    f32x16 acc0 = z16, acc1 = z16;    // qt = 0 / 1
    float ts0 = 0.f, ts1 = 0.f;

    auto expack = [&](const f32x16& s, float& ts, u32x4& o0, u32x4& o1) {
        float p[16];
#pragma unroll
        for (int r = 0; r < 16; ++r) p[r] = __builtin_exp2f(s[r]);
        ts += (((p[0]+p[1])+(p[2]+p[3])) + ((p[4]+p[5])+(p[6]+p[7])))
            + (((p[8]+p[9])+(p[10]+p[11])) + ((p[12]+p[13])+(p[14]+p[15])));
        const uint pk0 = cvt_pk_bf16(p[0],  p[1]);
        const uint pk1 = cvt_pk_bf16(p[2],  p[3]);
        const uint pk2 = cvt_pk_bf16(p[4],  p[5]);
        const uint pk3 = cvt_pk_bf16(p[6],  p[7]);
        const uint pk4 = cvt_pk_bf16(p[8],  p[9]);
        const uint pk5 = cvt_pk_bf16(p[10], p[11]);
        const uint pk6 = cvt_pk_bf16(p[12], p[13]);
        const uint pk7 = cvt_pk_bf16(p[14], p[15]);
        const u32x2 s02 = __builtin_amdgcn_permlane32_swap(pk0, pk2, false, false);
        const u32x2 s13 = __builtin_amdgcn_permlane32_swap(pk1, pk3, false, false);
        const u32x2 s46 = __builtin_amdgcn_permlane32_swap(pk4, pk6, false, false);
        const u32x2 s57 = __builtin_amdgcn_permlane32_swap(pk5, pk7, false, false);
        o0 = u32x4{ s02.x, s13.x, s02.y, s13.y };   // keys 8h5..+7   (ks0)
        o1 = u32x4{ s46.x, s57.x, s46.y, s57.y };   // keys 16+8h5..+7 (ks1)
    };

#pragma unroll 1
    for (int si = 0; si < 8; ++si) {
        const int db = si & 1;
        const int tile0 = si * 16;

        // ---- Phase A: S + expack for my 2 private chunks, both qt ----
        bf16x8 kf[2][2];
#pragma unroll
        for (int u = 0; u < 2; ++u) {
            const ushort* kr = kTb + (size_t)(tile0 + 2 * w + u) * 1024;
            kf[u][0] = *reinterpret_cast<const bf16x8*>(kr + lo8);
            kf[u][1] = *reinterpret_cast<const bf16x8*>(kr + 512 + lo8);
        }
        __builtin_amdgcn_sched_barrier(0);
#pragma unroll
        for (int u = 0; u < 2; ++u) {
            {
                f32x16 s = __builtin_amdgcn_mfma_f32_32x32x16_bf16(kf[u][0], qf[0][0], z16, 0, 0, 0);
                s = __builtin_amdgcn_mfma_f32_32x32x16_bf16(kf[u][1], qf[0][1], s, 0, 0, 0);
                u32x4 a0, a1;
                expack(s, ts0, a0, a1);
                pex[db][2 * w + u][0][0][lane] = a0;
                pex[db][2 * w + u][0][1][lane] = a1;
            }
            {
                f32x16 s = __builtin_amdgcn_mfma_f32_32x32x16_bf16(kf[u][0], qf[1][0], z16, 0, 0, 0);
                s = __builtin_amdgcn_mfma_f32_32x32x16_bf16(kf[u][1], qf[1][1], s, 0, 0, 0);
                u32x4 a0, a1;
                expack(s, ts1, a0, a1);
                pex[db][2 * w + u][1][0][lane] = a0;
                pex[db][2 * w + u][1][1][lane] = a1;
            }
        }

        sync_lds();   // ONE barrier per 512 keys; V/K loads stay in flight

        // ---- Phase B: PV over all 16 chunks, own 32 channels, both qt ----
#pragma unroll 4
        for (int cc = 0; cc < 16; ++cc) {
            const ushort* vb = vTb + (size_t)(tile0 + cc) * 1024;
            const bf16x8 v0 = *reinterpret_cast<const bf16x8*>(vb + lo8);
            const bf16x8 v1 = *reinterpret_cast<const bf16x8*>(vb + 512 + lo8);
            UB p00, p01, p10, p11;
            p00.u = pex[db][cc][0][0][lane];
            p01.u = pex[db][cc][0][1][lane];
            p10.u = pex[db][cc][1][0][lane];
            p11.u = pex[db][cc][1][1][lane];
            __builtin_amdgcn_s_setprio(1);
            acc0 = __builtin_amdgcn_mfma_f32_32x32x16_bf16(v0, p00.h, acc0, 0, 0, 0);
            acc0 = __builtin_amdgcn_mfma_f32_32x32x16_bf16(v1, p01.h, acc0, 0, 0, 0);
            acc1 = __builtin_amdgcn_mfma_f32_32x32x16_bf16(v0, p10.h, acc1, 0, 0, 0);
            acc1 = __builtin_amdgcn_mfma_f32_32x32x16_bf16(v1, p11.h, acc1, 0, 0, 0);
            __builtin_amdgcn_s_setprio(0);
        }
    }

    // ---- denominators: each wave's ts covers its private chunks ----
    ts0 += __shfl_xor(ts0, 32);
    ts1 += __shfl_xor(ts1, 32);
    if (lane < 32) { red[0][w][l31] = ts0; red[1][w][l31] = ts1; }
    __syncthreads();
    float d0 = 0.f, d1 = 0.f;
#pragma unroll
    for (int ww = 0; ww < 8; ++ww) { d0 += red[0][ww][l31]; d1 += red[1][ww][l31]; }
    const float inv0 = 1.0f / d0;
    const float inv1 = 1.0f / d1;

    // ---- direct store: wave owns disjoint 32ch x 64q ----
    float* ob = out + (size_t)b * CH * NN + i0;
#pragma unroll
    for (int r = 0; r < 16; ++r) {
        const int chl = 32 * w + (r & 3) + 8 * (r >> 2) + 4 * h5;
        ob[(size_t)chl * NN + l31]      = acc0[r] * inv0;
        ob[(size_t)chl * NN + 32 + l31] = acc1[r] * inv1;
    }
}

extern "C" void kernel_launch(void* const* d_in, const int* in_sizes, int n_in,
                              void* d_out, int out_size, void* d_ws, size_t ws_size,
                              hipStream_t stream) {
    const float* x  = (const float*)d_in[0];
    const float* Wq = (const float*)d_in[1];
    const float* bq = (const float*)d_in[2];
    const float* Wk = (const float*)d_in[3];
    const float* bk = (const float*)d_in[4];
    const float* Wv = (const float*)d_in[5];
    const float* bv = (const float*)d_in[6];
    float* out = (float*)d_out;

    ushort* ws = (ushort*)d_ws;
    ushort* qTf = ws;                                   // 4*128 tiles * 2KB = 1 MB
    ushort* kTf = qTf + (size_t)4 * 128 * 1024;         // 1 MB
    ushort* vf  = kTf + (size_t)4 * 128 * 1024;         // 4*8*128 tiles * 2KB = 8 MB

    proj_mfma<<<dim3(32, 5, 4), 256, 0, stream>>>(x, Wq, bq, Wk, bk, Wv, bv, qTf, kTf, vf);
    attn_v15<<<dim3(256), 512, 0, stream>>>(qTf, kTf, vf, out);
}